// Round 6
// baseline (105.408 us; speedup 1.0000x reference)
//
#include <hip/hip_runtime.h>

#define BATCH 8
#define NPTS 4096
#define KSEL 6          // K_NN + 1
#define ALPHA 1.05f
#define NSEG 16         // candidate-scan split per point (one wave each)
#define SEGLEN (NPTS / NSEG)   // 256
#define TPB (NSEG * 64)        // 1024 threads

typedef __attribute__((ext_vector_type(2))) float f32x2;

// --- single-inst 3-operand selection ops (R4) ---
static __device__ __forceinline__ unsigned min3u(unsigned a, unsigned b, unsigned c) {
  unsigned d;
  asm("v_min3_u32 %0, %1, %2, %3" : "=v"(d) : "v"(a), "v"(b), "v"(c));
  return d;
}
static __device__ __forceinline__ unsigned med3u(unsigned a, unsigned b, unsigned c) {
  unsigned d;
  asm("v_med3_u32 %0, %1, %2, %3" : "=v"(d) : "v"(a), "v"(b), "v"(c));
  return d;
}
static __device__ __forceinline__ unsigned max3u(unsigned a, unsigned b, unsigned c) {
  unsigned d;
  asm("v_max3_u32 %0, %1, %2, %3" : "=v"(d) : "v"(a), "v"(b), "v"(c));
  return d;
}
static __device__ __forceinline__ unsigned umn(unsigned a, unsigned b) { return a < b ? a : b; }
static __device__ __forceinline__ unsigned umx(unsigned a, unsigned b) { return a > b ? a : b; }

// --- packed fp32 (VOP3P): 2 independent fp32 ops per instruction ---
static __device__ __forceinline__ f32x2 pk_mul(f32x2 a, f32x2 b) {
  f32x2 d;
  asm("v_pk_mul_f32 %0, %1, %2" : "=v"(d) : "v"(a), "v"(b));
  return d;
}
static __device__ __forceinline__ f32x2 pk_add(f32x2 a, f32x2 b) {
  f32x2 d;
  asm("v_pk_add_f32 %0, %1, %2" : "=v"(d) : "v"(a), "v"(b));
  return d;
}
static __device__ __forceinline__ f32x2 pk_fma(f32x2 a, f32x2 b, f32x2 c) {
  f32x2 d;
  asm("v_pk_fma_f32 %0, %1, %2, %3" : "=v"(d) : "v"(a), "v"(b), "v"(c));
  return d;
}

#define FINF 0x7F800000u   // +inf bit pattern

// Fused branchless insert of two candidates into sorted m[0..5]
// (bit-identical to sequential insert; absmax 0.0 since R2).
static __device__ __forceinline__ void insert2(unsigned m[KSEL], unsigned tA, unsigned tB) {
#pragma unroll
  for (int k = 0; k < KSEL - 1; ++k) {
    const unsigned mk = m[k];
    m[k] = min3u(mk, tA, tB);
    const unsigned nA = med3u(mk, tA, tB);
    const unsigned nB = max3u(mk, tA, tB);
    tA = nA;
    tB = nB;
  }
  m[KSEL - 1] = min3u(m[KSEL - 1], tA, tB);
}

// ---------------------------------------------------------------------------
// Kernel 1: per-point mean 5-NN squared distance.
// grid = 512 blocks, block = 1024 threads (16 waves), 2 blocks/CU.
// LDS SoA {xs,ys,zs,ns}; distance via d = n_i + n_j - 2*dot (reference's own
// identity) computed 2-wide with v_pk_* -> 5 insts / 2 candidates.
// __launch_bounds__(1024,8): VGPR cap 64 (R5 post-mortem: compiler self-capped
// at 32 and strangled the unrolled body).
// ---------------------------------------------------------------------------
__global__ __launch_bounds__(TPB, 8) void knn_value_kernel(const float* __restrict__ pc,
                                                           float* __restrict__ value,
                                                           float* __restrict__ out) {
  __shared__ union __align__(16) {
    struct { float xs[NPTS]; float ys[NPTS]; float zs[NPTS]; float ns[NPTS]; } s;  // 64 KB
    unsigned cand[NSEG][64][KSEL];                                                 // 24 KB
  } sh;

  const int tid = threadIdx.x;
  const int pt  = tid & 63;
  const int seg = __builtin_amdgcn_readfirstlane(tid >> 6);  // wave-uniform
  const int b    = blockIdx.x >> 6;
  const int tile = blockIdx.x & 63;
  const int i    = tile * 64 + pt;

  if (blockIdx.x == 0 && tid == 0) out[0] = 0.0f;  // stats kernel accumulates

  const float* __restrict__ base = pc + (size_t)b * (NPTS * 3);

  // Stage SoA + norms. Thread t handles points 4t..4t+3 = float4s 3t..3t+2.
  {
    const float4* __restrict__ b4 = (const float4*)base;
    const float4 q0 = b4[tid * 3 + 0];   // x0 y0 z0 x1
    const float4 q1 = b4[tid * 3 + 1];   // y1 z1 x2 y2
    const float4 q2 = b4[tid * 3 + 2];   // z2 x3 y3 z3
    const int p0 = tid * 4;
    sh.s.xs[p0 + 0] = q0.x; sh.s.ys[p0 + 0] = q0.y; sh.s.zs[p0 + 0] = q0.z;
    sh.s.xs[p0 + 1] = q0.w; sh.s.ys[p0 + 1] = q1.x; sh.s.zs[p0 + 1] = q1.y;
    sh.s.xs[p0 + 2] = q1.z; sh.s.ys[p0 + 2] = q1.w; sh.s.zs[p0 + 2] = q2.x;
    sh.s.xs[p0 + 3] = q2.y; sh.s.ys[p0 + 3] = q2.z; sh.s.zs[p0 + 3] = q2.w;
    // norms with the same mul/fma chain as the dot product (self-dist == 0)
    sh.s.ns[p0 + 0] = fmaf(q0.z, q0.z, fmaf(q0.y, q0.y, q0.x * q0.x));
    sh.s.ns[p0 + 1] = fmaf(q1.y, q1.y, fmaf(q1.x, q1.x, q0.w * q0.w));
    sh.s.ns[p0 + 2] = fmaf(q2.x, q2.x, fmaf(q1.w, q1.w, q1.z * q1.z));
    sh.s.ns[p0 + 3] = fmaf(q2.w, q2.w, fmaf(q2.z, q2.z, q2.y * q2.y));
  }
  __syncthreads();

  const float xi = sh.s.xs[i];
  const float yi = sh.s.ys[i];
  const float zi = sh.s.zs[i];
  const float ni = sh.s.ns[i];
  const f32x2 xi2 = {xi, xi};
  const f32x2 yi2 = {yi, yi};
  const f32x2 zi2 = {zi, zi};
  const f32x2 ni2 = {ni, ni};
  const f32x2 n2m = {-2.0f, -2.0f};

  unsigned m[KSEL];
#pragma unroll
  for (int k = 0; k < KSEL; ++k) m[k] = FINF;

  const int j0 = seg * SEGLEN;
#pragma unroll 2
  for (int jj = 0; jj < SEGLEN; jj += 4) {
    // 4 wave-uniform candidates: 4x ds_read_b128 broadcast
    const float4 cx = *(const float4*)&sh.s.xs[j0 + jj];
    const float4 cy = *(const float4*)&sh.s.ys[j0 + jj];
    const float4 cz = *(const float4*)&sh.s.zs[j0 + jj];
    const float4 cn = *(const float4*)&sh.s.ns[j0 + jj];

    const f32x2 cx01 = {cx.x, cx.y}, cx23 = {cx.z, cx.w};
    const f32x2 cy01 = {cy.x, cy.y}, cy23 = {cy.z, cy.w};
    const f32x2 cz01 = {cz.x, cz.y}, cz23 = {cz.z, cz.w};
    const f32x2 cn01 = {cn.x, cn.y}, cn23 = {cn.z, cn.w};

    // d = fma(dot, -2, n_i + n_j), dot = ((x*cx) fma y*cy) fma z*cz
    f32x2 t01 = pk_mul(xi2, cx01);
    f32x2 t23 = pk_mul(xi2, cx23);
    t01 = pk_fma(yi2, cy01, t01);
    t23 = pk_fma(yi2, cy23, t23);
    t01 = pk_fma(zi2, cz01, t01);
    t23 = pk_fma(zi2, cz23, t23);
    const f32x2 s01 = pk_add(cn01, ni2);
    const f32x2 s23 = pk_add(cn23, ni2);
    const f32x2 d01 = pk_fma(t01, n2m, s01);
    const f32x2 d23 = pk_fma(t23, n2m, s23);

    insert2(m, __float_as_uint(d01.x), __float_as_uint(d01.y));
    insert2(m, __float_as_uint(d23.x), __float_as_uint(d23.y));
  }
  __syncthreads();  // everyone done reading the stage buffer

#pragma unroll
  for (int k = 0; k < KSEL; ++k) sh.cand[seg][pt][k] = m[k];
  __syncthreads();

  // Tree-merge the 16 sorted lists per point: 8,4,2,1 pairwise merges.
  for (int st = 1; st < NSEG; st <<= 1) {
    const int pairs = NSEG / (2 * st);
    if (tid < pairs * 64) {
      const int q = tid >> 6;
      const int p = tid & 63;
      unsigned* A = &sh.cand[2 * st * q][p][0];
      const unsigned* B = &sh.cand[2 * st * q + st][p][0];
      unsigned mm[KSEL];
#pragma unroll
      for (int k = 0; k < KSEL; ++k) mm[k] = A[k];
#pragma unroll
      for (int k = 0; k < KSEL; ++k) {
        unsigned t = B[k];
#pragma unroll
        for (int u = 0; u < KSEL - 1; ++u) {
          const unsigned lo = umn(mm[u], t);
          t = umx(mm[u], t);
          mm[u] = lo;
        }
        mm[KSEL - 1] = umn(mm[KSEL - 1], t);
      }
#pragma unroll
      for (int k = 0; k < KSEL; ++k) A[k] = mm[k];
    }
    __syncthreads();
  }

  // drop the smallest (self-distance 0), mean of remaining 5
  if (tid < 64) {
    float s5 = 0.f;
#pragma unroll
    for (int k = 1; k < KSEL; ++k) s5 += __uint_as_float(sh.cand[0][tid][k]);
    value[b * NPTS + tile * 64 + tid] = s5 * 0.2f;
  }
}

// ---------------------------------------------------------------------------
// Kernel 2: per-batch mean / unbiased std / threshold / masked mean * weight,
// then atomicAdd of loss*(1/BATCH) into out (zeroed by kernel 1).
// ---------------------------------------------------------------------------
__global__ __launch_bounds__(256) void stats_kernel(const float* __restrict__ value,
                                                    const float* __restrict__ weights,
                                                    float* __restrict__ out) {
  __shared__ float red[256];
  const int b   = blockIdx.x;
  const int tid = threadIdx.x;
  const float* __restrict__ v = value + b * NPTS;

  float s = 0.f;
  for (int j = tid; j < NPTS; j += 256) s += v[j];
  red[tid] = s;
  __syncthreads();
  for (int off = 128; off > 0; off >>= 1) {
    if (tid < off) red[tid] += red[tid + off];
    __syncthreads();
  }
  const float mean = red[0] * (1.0f / NPTS);
  __syncthreads();

  float s2 = 0.f;
  for (int j = tid; j < NPTS; j += 256) {
    const float d = v[j] - mean;
    s2 += d * d;
  }
  red[tid] = s2;
  __syncthreads();
  for (int off = 128; off > 0; off >>= 1) {
    if (tid < off) red[tid] += red[tid + off];
    __syncthreads();
  }
  const float thr = mean + ALPHA * sqrtf(red[0] * (1.0f / (NPTS - 1)));
  __syncthreads();

  float s3 = 0.f;
  for (int j = tid; j < NPTS; j += 256) {
    const float vv = v[j];
    if (vv > thr) s3 += vv;
  }
  red[tid] = s3;
  __syncthreads();
  for (int off = 128; off > 0; off >>= 1) {
    if (tid < off) red[tid] += red[tid + off];
    __syncthreads();
  }
  if (tid == 0) {
    atomicAdd(out, red[0] * (1.0f / NPTS) * weights[b] * (1.0f / BATCH));
  }
}

extern "C" void kernel_launch(void* const* d_in, const int* in_sizes, int n_in,
                              void* d_out, int out_size, void* d_ws, size_t ws_size,
                              hipStream_t stream) {
  const float* pc      = (const float*)d_in[0];   // [8,4096,3] f32
  const float* weights = (const float*)d_in[1];   // [8] f32
  float* out   = (float*)d_out;                   // scalar f32
  float* value = (float*)d_ws;                    // [8*4096] f32

  knn_value_kernel<<<dim3(BATCH * (NPTS / 64)), dim3(TPB), 0, stream>>>(pc, value, out);
  stats_kernel<<<dim3(BATCH), dim3(256), 0, stream>>>(value, weights, out);
}